// Round 1
// baseline (140.995 us; speedup 1.0000x reference)
//
#include <hip/hip_runtime.h>

#define Bn 4
#define Dd 128
#define Hh 192
#define Ww 192

// ---------------- Kernel A: per-batch affine matrices ----------------
__global__ void mats_kernel(const float* __restrict__ rot0,
                            const float* __restrict__ rot1,
                            const float* __restrict__ rot2,
                            const float* __restrict__ tr1,
                            const float* __restrict__ tr2,
                            const float* __restrict__ cp,
                            float* __restrict__ mats) {
    int b = threadIdx.x;
    if (b >= Bn) return;
    float z = rot0[b], y = rot1[b], x = rot2[b];
    float cz = cosf(z), sz = sinf(z);
    float cy = cosf(y), sy = sinf(y);
    float cx = cosf(x), sx = sinf(x);
    // R = Z(z) @ Y(y) @ X(x)
    float R00 = cz * cy;
    float R01 = -sz * cx + cz * sy * sx;
    float R02 = sz * sx + cz * sy * cx;
    float R10 = sz * cy;
    float R11 = cz * cx + sz * sy * sx;
    float R12 = -cz * sx + sz * sy * cx;
    float R20 = -sy;
    float R21 = cy * sx;
    float R22 = cy * cx;
    float c0 = cp[b * 3 + 0], c1 = cp[b * 3 + 1], c2 = cp[b * 3 + 2];
    float tz = 0.0f;
    float ty = tr1[b] * (float)Hh;
    float tx = tr2[b] * (float)Ww;
    // mat[:3,3] = -R@c + t + c
    float m03 = -(R00 * c0 + R01 * c1 + R02 * c2) + tz + c0;
    float m13 = -(R10 * c0 + R11 * c1 + R12 * c2) + ty + c1;
    float m23 = -(R20 * c0 + R21 * c1 + R22 * c2) + tx + c2;
    float* M = mats + b * 12;
    M[0] = R00; M[1]  = R01; M[2]  = R02; M[3]  = m03;
    M[4] = R10; M[5]  = R11; M[6]  = R12; M[7]  = m13;
    M[8] = R20; M[9]  = R21; M[10] = R22; M[11] = m23;
}

// ---------------- Kernel B: warp + mean + y passthrough ----------------
__global__ __launch_bounds__(Ww) void warp_kernel(const float* __restrict__ x,
                                                  const float* __restrict__ yin,
                                                  const float* __restrict__ mats,
                                                  float* __restrict__ out) {
    const int w = threadIdx.x;   // 0..191
    const int h = blockIdx.x;    // 0..191
    const int b = blockIdx.y;    // 0..3

    const float* M = mats + b * 12;
    const float dz = M[0], dy = M[4], dx = M[8];
    const float gz0 = M[1] * (float)h + M[2] * (float)w + M[3];
    const float gy0 = M[5] * (float)h + M[6] * (float)w + M[7];
    const float gx0 = M[9] * (float)h + M[10] * (float)w + M[11];

    const float* __restrict__ V = x + (size_t)b * (Dd * Hh * Ww);

    const size_t warp_base = (size_t)Bn * Hh * Ww;             // x_2d elements
    float* __restrict__ owarp = out + warp_base +
                                (size_t)b * (Dd * Hh * Ww) + (size_t)h * Ww + w;

    float sum = 0.0f;

    #pragma unroll 4
    for (int d = 0; d < Dd; ++d) {
        const float gz = fmaf(dz, (float)d, gz0);
        const float gy = fmaf(dy, (float)d, gy0);
        const float gx = fmaf(dx, (float)d, gx0);

        const float fz = floorf(gz), fy = floorf(gy), fx = floorf(gx);
        const float tz = gz - fz, ty = gy - fy, tx = gx - fx;
        const int iz = (int)fz, iy = (int)fy, ix = (int)fx;

        const int iz1 = iz + 1, iy1 = iy + 1, ix1 = ix + 1;

        const float wz0 = ((unsigned)iz  < (unsigned)Dd) ? (1.0f - tz) : 0.0f;
        const float wz1 = ((unsigned)iz1 < (unsigned)Dd) ? tz : 0.0f;
        const float wy0 = ((unsigned)iy  < (unsigned)Hh) ? (1.0f - ty) : 0.0f;
        const float wy1 = ((unsigned)iy1 < (unsigned)Hh) ? ty : 0.0f;
        const float wx0 = ((unsigned)ix  < (unsigned)Ww) ? (1.0f - tx) : 0.0f;
        const float wx1 = ((unsigned)ix1 < (unsigned)Ww) ? tx : 0.0f;

        const int iz0c = min(max(iz, 0), Dd - 1);
        const int iz1c = min(max(iz1, 0), Dd - 1);
        const int iy0c = min(max(iy, 0), Hh - 1);
        const int iy1c = min(max(iy1, 0), Hh - 1);
        const int ix0c = min(max(ix, 0), Ww - 1);
        const int ix1c = min(max(ix1, 0), Ww - 1);

        const float* p00 = V + (size_t)iz0c * (Hh * Ww) + iy0c * Ww;
        const float* p01 = V + (size_t)iz0c * (Hh * Ww) + iy1c * Ww;
        const float* p10 = V + (size_t)iz1c * (Hh * Ww) + iy0c * Ww;
        const float* p11 = V + (size_t)iz1c * (Hh * Ww) + iy1c * Ww;

        const float v000 = p00[ix0c], v001 = p00[ix1c];
        const float v010 = p01[ix0c], v011 = p01[ix1c];
        const float v100 = p10[ix0c], v101 = p10[ix1c];
        const float v110 = p11[ix0c], v111 = p11[ix1c];

        const float vz0 = wy0 * (wx0 * v000 + wx1 * v001) +
                          wy1 * (wx0 * v010 + wx1 * v011);
        const float vz1 = wy0 * (wx0 * v100 + wx1 * v101) +
                          wy1 * (wx0 * v110 + wx1 * v111);
        const float val = wz0 * vz0 + wz1 * vz1;

        owarp[(size_t)d * (Hh * Ww)] = val;
        sum += val;
    }

    const int idx2d = (b * Hh + h) * Ww + w;
    out[idx2d] = sum * (1.0f / (float)Dd);                       // x_2d
    out[warp_base + (size_t)Bn * Dd * Hh * Ww + idx2d] = yin[idx2d]; // y
}

extern "C" void kernel_launch(void* const* d_in, const int* in_sizes, int n_in,
                              void* d_out, int out_size, void* d_ws, size_t ws_size,
                              hipStream_t stream) {
    const float* x    = (const float*)d_in[0];
    const float* yin  = (const float*)d_in[1];
    const float* rot0 = (const float*)d_in[2];
    const float* rot1 = (const float*)d_in[3];
    const float* rot2 = (const float*)d_in[4];
    const float* tr1  = (const float*)d_in[5];
    const float* tr2  = (const float*)d_in[6];
    const float* cp   = (const float*)d_in[7];

    float* mats = (float*)d_ws;

    mats_kernel<<<1, 64, 0, stream>>>(rot0, rot1, rot2, tr1, tr2, cp, mats);

    dim3 grid(Hh, Bn);
    warp_kernel<<<grid, Ww, 0, stream>>>(x, yin, mats, (float*)d_out);
}

// Round 2
// 124.499 us; speedup vs baseline: 1.1325x; 1.1325x over previous
//
#include <hip/hip_runtime.h>

#define Bn 4
#define Dd 128
#define Hh 192
#define Ww 192
#define DCH 8           // d-chunks per (b,h)
#define DPB (Dd / DCH)  // 16 d-values per block

#define PLANE (Hh * Ww)           // 36864
#define VOL   (Dd * PLANE)        // per-batch x elements
#define N2D   (Bn * PLANE)        // x_2d / y elements
#define WARP_OFF ((size_t)N2D)    // x_warp offset in out
#define Y_OFF (WARP_OFF + (size_t)Bn * VOL)

// ---------------- Kernel A: per-batch affine matrices ----------------
__global__ void mats_kernel(const float* __restrict__ rot0,
                            const float* __restrict__ rot1,
                            const float* __restrict__ rot2,
                            const float* __restrict__ tr1,
                            const float* __restrict__ tr2,
                            const float* __restrict__ cp,
                            float* __restrict__ mats) {
    int b = threadIdx.x;
    if (b >= Bn) return;
    float z = rot0[b], y = rot1[b], x = rot2[b];
    float cz = cosf(z), sz = sinf(z);
    float cy = cosf(y), sy = sinf(y);
    float cx = cosf(x), sx = sinf(x);
    float R00 = cz * cy;
    float R01 = -sz * cx + cz * sy * sx;
    float R02 = sz * sx + cz * sy * cx;
    float R10 = sz * cy;
    float R11 = cz * cx + sz * sy * sx;
    float R12 = -cz * sx + sz * sy * cx;
    float R20 = -sy;
    float R21 = cy * sx;
    float R22 = cy * cx;
    float c0 = cp[b * 3 + 0], c1 = cp[b * 3 + 1], c2 = cp[b * 3 + 2];
    float ty = tr1[b] * (float)Hh;
    float tx = tr2[b] * (float)Ww;
    float m03 = -(R00 * c0 + R01 * c1 + R02 * c2) + c0;
    float m13 = -(R10 * c0 + R11 * c1 + R12 * c2) + ty + c1;
    float m23 = -(R20 * c0 + R21 * c1 + R22 * c2) + tx + c2;
    float* M = mats + b * 12;
    M[0] = R00; M[1]  = R01; M[2]  = R02; M[3]  = m03;
    M[4] = R10; M[5]  = R11; M[6]  = R12; M[7]  = m13;
    M[8] = R20; M[9]  = R21; M[10] = R22; M[11] = m23;
}

// ---------------- Kernel B: warp (d-chunked) + per-chunk partial sums ----
// NT: use non-temporal stores for x_warp (write-only in partial-sum path)
template <bool NT>
__global__ __launch_bounds__(Ww) void warp_kernel(const float* __restrict__ x,
                                                  const float* __restrict__ mats,
                                                  float* __restrict__ out,
                                                  float* __restrict__ partial) {
    const int w = threadIdx.x;   // 0..191
    const int h = blockIdx.x;    // 0..191
    const int c = blockIdx.y;    // 0..DCH-1
    const int b = blockIdx.z;    // 0..3
    const int d0 = c * DPB;

    const float* M = mats + b * 12;
    const float dz = M[0], dy = M[4], dx = M[8];
    const float gzb = fmaf(M[0], (float)d0, M[1] * (float)h + M[2] * (float)w + M[3]);
    const float gyb = fmaf(M[4], (float)d0, M[5] * (float)h + M[6] * (float)w + M[7]);
    const float gxb = fmaf(M[8], (float)d0, M[9] * (float)h + M[10] * (float)w + M[11]);

    const float* __restrict__ V = x + (size_t)b * VOL;
    float* __restrict__ owarp = out + WARP_OFF + (size_t)b * VOL +
                                (size_t)d0 * PLANE + (size_t)h * Ww + w;

    float sum = 0.0f;

    #pragma unroll 4
    for (int k = 0; k < DPB; ++k) {
        const float gz = fmaf(dz, (float)k, gzb);
        const float gy = fmaf(dy, (float)k, gyb);
        const float gx = fmaf(dx, (float)k, gxb);

        const float fz = floorf(gz), fy = floorf(gy), fx = floorf(gx);
        const float tz = gz - fz, ty = gy - fy, tx = gx - fx;
        const int iz = (int)fz, iy = (int)fy, ix = (int)fx;
        const int iz1 = iz + 1, iy1 = iy + 1, ix1 = ix + 1;

        const float wz0 = ((unsigned)iz  < (unsigned)Dd) ? (1.0f - tz) : 0.0f;
        const float wz1 = ((unsigned)iz1 < (unsigned)Dd) ? tz : 0.0f;
        const float wy0 = ((unsigned)iy  < (unsigned)Hh) ? (1.0f - ty) : 0.0f;
        const float wy1 = ((unsigned)iy1 < (unsigned)Hh) ? ty : 0.0f;
        const float wx0 = ((unsigned)ix  < (unsigned)Ww) ? (1.0f - tx) : 0.0f;
        const float wx1 = ((unsigned)ix1 < (unsigned)Ww) ? tx : 0.0f;

        const int iz0c = min(max(iz, 0), Dd - 1);
        const int iz1c = min(max(iz1, 0), Dd - 1);
        const int iy0c = min(max(iy, 0), Hh - 1);
        const int iy1c = min(max(iy1, 0), Hh - 1);
        const int ix0c = min(max(ix, 0), Ww - 1);
        const int ix1c = min(max(ix1, 0), Ww - 1);

        const float* p00 = V + (size_t)iz0c * PLANE + iy0c * Ww;
        const float* p01 = V + (size_t)iz0c * PLANE + iy1c * Ww;
        const float* p10 = V + (size_t)iz1c * PLANE + iy0c * Ww;
        const float* p11 = V + (size_t)iz1c * PLANE + iy1c * Ww;

        const float v000 = p00[ix0c], v001 = p00[ix1c];
        const float v010 = p01[ix0c], v011 = p01[ix1c];
        const float v100 = p10[ix0c], v101 = p10[ix1c];
        const float v110 = p11[ix0c], v111 = p11[ix1c];

        const float vz0 = wy0 * (wx0 * v000 + wx1 * v001) +
                          wy1 * (wx0 * v010 + wx1 * v011);
        const float vz1 = wy0 * (wx0 * v100 + wx1 * v101) +
                          wy1 * (wx0 * v110 + wx1 * v111);
        const float val = wz0 * vz0 + wz1 * vz1;

        if (NT) {
            __builtin_nontemporal_store(val, &owarp[(size_t)k * PLANE]);
        } else {
            owarp[(size_t)k * PLANE] = val;
        }
        sum += val;
    }

    partial[((size_t)(b * DCH + c) * Hh + h) * Ww + w] = sum;
}

// ---------------- Kernel C: reduce partials -> x_2d, copy y -------------
__global__ __launch_bounds__(256) void reduce_kernel(const float* __restrict__ partial,
                                                     const float* __restrict__ yin,
                                                     float* __restrict__ out) {
    const int idx = blockIdx.x * 256 + threadIdx.x;   // 0..N2D-1
    if (idx >= N2D) return;
    const int b = idx / PLANE;
    const int rem = idx - b * PLANE;
    const float* p = partial + (size_t)b * DCH * PLANE + rem;
    float s = 0.0f;
    #pragma unroll
    for (int c = 0; c < DCH; ++c) s += p[(size_t)c * PLANE];
    out[idx] = s * (1.0f / (float)Dd);
    out[Y_OFF + idx] = yin[idx];
}

// ---------------- Fallback reduce: read x_warp directly -----------------
__global__ __launch_bounds__(256) void reduce_fallback_kernel(const float* __restrict__ yin,
                                                              float* __restrict__ out) {
    const int idx = blockIdx.x * 256 + threadIdx.x;
    if (idx >= N2D) return;
    const int b = idx / PLANE;
    const int rem = idx - b * PLANE;
    const float* p = out + WARP_OFF + (size_t)b * VOL + rem;
    float s = 0.0f;
    #pragma unroll 8
    for (int d = 0; d < Dd; ++d) s += p[(size_t)d * PLANE];
    out[idx] = s * (1.0f / (float)Dd);
    out[Y_OFF + idx] = yin[idx];
}

extern "C" void kernel_launch(void* const* d_in, const int* in_sizes, int n_in,
                              void* d_out, int out_size, void* d_ws, size_t ws_size,
                              hipStream_t stream) {
    const float* x    = (const float*)d_in[0];
    const float* yin  = (const float*)d_in[1];
    const float* rot0 = (const float*)d_in[2];
    const float* rot1 = (const float*)d_in[3];
    const float* rot2 = (const float*)d_in[4];
    const float* tr1  = (const float*)d_in[5];
    const float* tr2  = (const float*)d_in[6];
    const float* cp   = (const float*)d_in[7];

    float* mats = (float*)d_ws;
    float* partial = (float*)d_ws + 64;
    const size_t need = (64 + (size_t)Bn * DCH * PLANE) * sizeof(float);

    mats_kernel<<<1, 64, 0, stream>>>(rot0, rot1, rot2, tr1, tr2, cp, mats);

    dim3 grid(Hh, DCH, Bn);
    if (ws_size >= need) {
        warp_kernel<true><<<grid, Ww, 0, stream>>>(x, mats, (float*)d_out, partial);
        reduce_kernel<<<(N2D + 255) / 256, 256, 0, stream>>>(partial, yin, (float*)d_out);
    } else {
        warp_kernel<false><<<grid, Ww, 0, stream>>>(x, mats, (float*)d_out, mats /*unused*/);
        reduce_fallback_kernel<<<(N2D + 255) / 256, 256, 0, stream>>>(yin, (float*)d_out);
    }
}

// Round 3
// 82.796 us; speedup vs baseline: 1.7029x; 1.5037x over previous
//
#include <hip/hip_runtime.h>

#define Bn 4
#define Dd 128
#define Hh 192
#define Ww 192
#define DCH 8           // d-chunks per (b,h)
#define DPB (Dd / DCH)  // 16 d-values per block

#define PLANE (Hh * Ww)           // 36864
#define VOL   (Dd * PLANE)        // per-batch x elements
#define N2D   (Bn * PLANE)        // x_2d / y elements
#define WARP_OFF ((size_t)N2D)    // x_warp offset in out
#define Y_OFF (WARP_OFF + (size_t)Bn * VOL)

typedef float f2 __attribute__((ext_vector_type(2)));
typedef f2 __attribute__((aligned(4))) f2u;   // 4B-aligned float2 load

__device__ __forceinline__ f2 load2(const float* p) {
    return *(const f2u*)p;
}

// ---------------- Kernel A: per-batch affine matrices ----------------
__global__ void mats_kernel(const float* __restrict__ rot0,
                            const float* __restrict__ rot1,
                            const float* __restrict__ rot2,
                            const float* __restrict__ tr1,
                            const float* __restrict__ tr2,
                            const float* __restrict__ cp,
                            float* __restrict__ mats) {
    int b = threadIdx.x;
    if (b >= Bn) return;
    float z = rot0[b], y = rot1[b], x = rot2[b];
    float cz = cosf(z), sz = sinf(z);
    float cy = cosf(y), sy = sinf(y);
    float cx = cosf(x), sx = sinf(x);
    float R00 = cz * cy;
    float R01 = -sz * cx + cz * sy * sx;
    float R02 = sz * sx + cz * sy * cx;
    float R10 = sz * cy;
    float R11 = cz * cx + sz * sy * sx;
    float R12 = -cz * sx + sz * sy * cx;
    float R20 = -sy;
    float R21 = cy * sx;
    float R22 = cy * cx;
    float c0 = cp[b * 3 + 0], c1 = cp[b * 3 + 1], c2 = cp[b * 3 + 2];
    float ty = tr1[b] * (float)Hh;
    float tx = tr2[b] * (float)Ww;
    float m03 = -(R00 * c0 + R01 * c1 + R02 * c2) + c0;
    float m13 = -(R10 * c0 + R11 * c1 + R12 * c2) + ty + c1;
    float m23 = -(R20 * c0 + R21 * c1 + R22 * c2) + tx + c2;
    float* M = mats + b * 12;
    M[0] = R00; M[1]  = R01; M[2]  = R02; M[3]  = m03;
    M[4] = R10; M[5]  = R11; M[6]  = R12; M[7]  = m13;
    M[8] = R20; M[9]  = R21; M[10] = R22; M[11] = m23;
}

// ---------------- Kernel B: warp (d-chunked) + per-chunk partial sums ----
// Grid: 6144 blocks, XCD-swizzled so each XCD owns 4 contiguous (b,c) slabs
// (slab read footprint ~2.5 MB -> fits 4 MB per-XCD L2).
template <bool NT>
__global__ __launch_bounds__(Ww) void warp_kernel(const float* __restrict__ x,
                                                  const float* __restrict__ mats,
                                                  float* __restrict__ out,
                                                  float* __restrict__ partial) {
    // ---- XCD-aware decode: g -> (b, c, h) ----
    const int g   = blockIdx.x;          // 0..6143
    const int xcd = g & 7;               // HW round-robins blocks over 8 XCDs
    const int i   = g >> 3;              // 0..767 within this XCD
    const int wl  = xcd * (Bn * DCH * Hh / 8) + i;  // xcd*768 + i
    const int h   = wl % Hh;
    const int bc  = wl / Hh;             // 0..31
    const int b   = bc >> 3;
    const int c   = bc & 7;

    const int w  = threadIdx.x;          // 0..191
    const int d0 = c * DPB;

    const float* M = mats + b * 12;
    const float dz = M[0], dy = M[4], dx = M[8];
    const float gzb = fmaf(M[0], (float)d0, M[1] * (float)h + M[2] * (float)w + M[3]);
    const float gyb = fmaf(M[4], (float)d0, M[5] * (float)h + M[6] * (float)w + M[7]);
    const float gxb = fmaf(M[8], (float)d0, M[9] * (float)h + M[10] * (float)w + M[11]);

    const float* __restrict__ V = x + (size_t)b * VOL;
    float* __restrict__ owarp = out + WARP_OFF + (size_t)b * VOL +
                                (size_t)d0 * PLANE + (size_t)h * Ww + w;

    float sum = 0.0f;

    #pragma unroll 2
    for (int k = 0; k < DPB; ++k) {
        const float gz = fmaf(dz, (float)k, gzb);
        const float gy = fmaf(dy, (float)k, gyb);
        const float gx = fmaf(dx, (float)k, gxb);

        const float fz = floorf(gz), fy = floorf(gy), fx = floorf(gx);
        const float tz = gz - fz, ty = gy - fy, tx = gx - fx;
        const int iz = (int)fz, iy = (int)fy, ix = (int)fx;

        // validity-masked weights
        const float wz0 = ((unsigned)iz       < (unsigned)Dd) ? (1.0f - tz) : 0.0f;
        const float wz1 = ((unsigned)(iz + 1) < (unsigned)Dd) ? tz : 0.0f;
        const float wy0 = ((unsigned)iy       < (unsigned)Hh) ? (1.0f - ty) : 0.0f;
        const float wy1 = ((unsigned)(iy + 1) < (unsigned)Hh) ? ty : 0.0f;
        const float wx0 = ((unsigned)ix       < (unsigned)Ww) ? (1.0f - tx) : 0.0f;
        const float wx1 = ((unsigned)(ix + 1) < (unsigned)Ww) ? tx : 0.0f;

        // fold x-tap selection into two weights on the dwordx2 pair:
        // window [ixl, ixl+1], ixl = clamp(ix, 0, Ww-2)
        //   v000 = (ix >= Ww-1) ? hi : lo ; v001 = (ix >= 0) ? hi : lo
        // contribution = wx0*v000 + wx1*v001 = WL*lo + WH*hi
        const bool right  = (ix >= Ww - 1);
        const bool leftok = (ix >= 0);
        const float WL = (right ? 0.0f : wx0) + (leftok ? 0.0f : wx1);
        const float WH = (right ? wx0 : 0.0f) + (leftok ? wx1 : 0.0f);

        const int iz0c = min(max(iz, 0), Dd - 1);
        const int iz1c = min(max(iz + 1, 0), Dd - 1);
        const int iy0c = min(max(iy, 0), Hh - 1);
        const int iy1c = min(max(iy + 1, 0), Hh - 1);
        const int ixl  = min(max(ix, 0), Ww - 2);

        const size_t z0 = (size_t)iz0c * PLANE;
        const size_t z1 = (size_t)iz1c * PLANE;
        const int    y0 = iy0c * Ww + ixl;
        const int    y1 = iy1c * Ww + ixl;

        const f2 q00 = load2(V + z0 + y0);
        const f2 q01 = load2(V + z0 + y1);
        const f2 q10 = load2(V + z1 + y0);
        const f2 q11 = load2(V + z1 + y1);

        const float v00 = fmaf(WL, q00.x, WH * q00.y);
        const float v01 = fmaf(WL, q01.x, WH * q01.y);
        const float v10 = fmaf(WL, q10.x, WH * q10.y);
        const float v11 = fmaf(WL, q11.x, WH * q11.y);

        const float vz0 = fmaf(wy0, v00, wy1 * v01);
        const float vz1 = fmaf(wy0, v10, wy1 * v11);
        const float val = fmaf(wz0, vz0, wz1 * vz1);

        if (NT) {
            __builtin_nontemporal_store(val, &owarp[(size_t)k * PLANE]);
        } else {
            owarp[(size_t)k * PLANE] = val;
        }
        sum += val;
    }

    partial[((size_t)(b * DCH + c) * Hh + h) * Ww + w] = sum;
}

// ---------------- Kernel C: reduce partials -> x_2d, copy y -------------
__global__ __launch_bounds__(256) void reduce_kernel(const float* __restrict__ partial,
                                                     const float* __restrict__ yin,
                                                     float* __restrict__ out) {
    const int idx = blockIdx.x * 256 + threadIdx.x;   // 0..N2D-1
    if (idx >= N2D) return;
    const int b = idx / PLANE;
    const int rem = idx - b * PLANE;
    const float* p = partial + (size_t)b * DCH * PLANE + rem;
    float s = 0.0f;
    #pragma unroll
    for (int c = 0; c < DCH; ++c) s += p[(size_t)c * PLANE];
    out[idx] = s * (1.0f / (float)Dd);
    out[Y_OFF + idx] = yin[idx];
}

// ---------------- Fallback reduce: read x_warp directly -----------------
__global__ __launch_bounds__(256) void reduce_fallback_kernel(const float* __restrict__ yin,
                                                              float* __restrict__ out) {
    const int idx = blockIdx.x * 256 + threadIdx.x;
    if (idx >= N2D) return;
    const int b = idx / PLANE;
    const int rem = idx - b * PLANE;
    const float* p = out + WARP_OFF + (size_t)b * VOL + rem;
    float s = 0.0f;
    #pragma unroll 8
    for (int d = 0; d < Dd; ++d) s += p[(size_t)d * PLANE];
    out[idx] = s * (1.0f / (float)Dd);
    out[Y_OFF + idx] = yin[idx];
}

extern "C" void kernel_launch(void* const* d_in, const int* in_sizes, int n_in,
                              void* d_out, int out_size, void* d_ws, size_t ws_size,
                              hipStream_t stream) {
    const float* x    = (const float*)d_in[0];
    const float* yin  = (const float*)d_in[1];
    const float* rot0 = (const float*)d_in[2];
    const float* rot1 = (const float*)d_in[3];
    const float* rot2 = (const float*)d_in[4];
    const float* tr1  = (const float*)d_in[5];
    const float* tr2  = (const float*)d_in[6];
    const float* cp   = (const float*)d_in[7];

    float* mats = (float*)d_ws;
    float* partial = (float*)d_ws + 64;
    const size_t need = (64 + (size_t)Bn * DCH * PLANE) * sizeof(float);

    mats_kernel<<<1, 64, 0, stream>>>(rot0, rot1, rot2, tr1, tr2, cp, mats);

    const int nblocks = Bn * DCH * Hh;   // 6144
    if (ws_size >= need) {
        warp_kernel<true><<<nblocks, Ww, 0, stream>>>(x, mats, (float*)d_out, partial);
        reduce_kernel<<<(N2D + 255) / 256, 256, 0, stream>>>(partial, yin, (float*)d_out);
    } else {
        warp_kernel<false><<<nblocks, Ww, 0, stream>>>(x, mats, (float*)d_out, mats /*unused*/);
        reduce_fallback_kernel<<<(N2D + 255) / 256, 256, 0, stream>>>(yin, (float*)d_out);
    }
}

// Round 4
// 81.669 us; speedup vs baseline: 1.7264x; 1.0138x over previous
//
#include <hip/hip_runtime.h>

#define Bn 4
#define Dd 128
#define Hh 192
#define Ww 192
#define DCH 8           // d-chunks per (b,h)
#define DPB (Dd / DCH)  // 16 d-values per block

#define PLANE (Hh * Ww)           // 36864
#define VOL   (Dd * PLANE)        // per-batch x elements
#define N2D   (Bn * PLANE)        // x_2d / y elements
#define WARP_OFF ((size_t)N2D)    // x_warp offset in out
#define Y_OFF (WARP_OFF + (size_t)Bn * VOL)

typedef float f2 __attribute__((ext_vector_type(2)));
typedef f2 __attribute__((aligned(4))) f2u;   // 4B-aligned float2 load

__device__ __forceinline__ f2 load2(const float* p) {
    return *(const f2u*)p;
}

// ---------------- Kernel A: per-batch affine matrices ----------------
__global__ void mats_kernel(const float* __restrict__ rot0,
                            const float* __restrict__ rot1,
                            const float* __restrict__ rot2,
                            const float* __restrict__ tr1,
                            const float* __restrict__ tr2,
                            const float* __restrict__ cp,
                            float* __restrict__ mats) {
    int b = threadIdx.x;
    if (b >= Bn) return;
    float z = rot0[b], y = rot1[b], x = rot2[b];
    float cz = cosf(z), sz = sinf(z);
    float cy = cosf(y), sy = sinf(y);
    float cx = cosf(x), sx = sinf(x);
    float R00 = cz * cy;
    float R01 = -sz * cx + cz * sy * sx;
    float R02 = sz * sx + cz * sy * cx;
    float R10 = sz * cy;
    float R11 = cz * cx + sz * sy * sx;
    float R12 = -cz * sx + sz * sy * cx;
    float R20 = -sy;
    float R21 = cy * sx;
    float R22 = cy * cx;
    float c0 = cp[b * 3 + 0], c1 = cp[b * 3 + 1], c2 = cp[b * 3 + 2];
    float ty = tr1[b] * (float)Hh;
    float tx = tr2[b] * (float)Ww;
    float m03 = -(R00 * c0 + R01 * c1 + R02 * c2) + c0;
    float m13 = -(R10 * c0 + R11 * c1 + R12 * c2) + ty + c1;
    float m23 = -(R20 * c0 + R21 * c1 + R22 * c2) + tx + c2;
    float* M = mats + b * 12;
    M[0] = R00; M[1]  = R01; M[2]  = R02; M[3]  = m03;
    M[4] = R10; M[5]  = R11; M[6]  = R12; M[7]  = m13;
    M[8] = R20; M[9]  = R21; M[10] = R22; M[11] = m23;
}

// ---------------- Kernel B: warp (d-chunked) + per-chunk partial sums ----
// XCD-swizzled grid; 4-step groups with batched loads for MLP.
template <bool NT>
__global__ __launch_bounds__(Ww) void warp_kernel(const float* __restrict__ x,
                                                  const float* __restrict__ mats,
                                                  float* __restrict__ out,
                                                  float* __restrict__ partial) {
    // ---- XCD-aware decode: g -> (b, c, h) ----
    const int g   = blockIdx.x;          // 0..6143
    const int xcd = g & 7;               // HW round-robins blocks over 8 XCDs
    const int i   = g >> 3;              // 0..767 within this XCD
    const int wl  = xcd * (Bn * DCH * Hh / 8) + i;  // xcd*768 + i
    const int h   = wl % Hh;
    const int bc  = wl / Hh;             // 0..31
    const int b   = bc >> 3;
    const int c   = bc & 7;

    const int w  = threadIdx.x;          // 0..191
    const int d0 = c * DPB;

    const float* M = mats + b * 12;
    const float dz = M[0], dy = M[4], dx = M[8];
    const float gzb = fmaf(M[0], (float)d0, M[1] * (float)h + M[2] * (float)w + M[3]);
    const float gyb = fmaf(M[4], (float)d0, M[5] * (float)h + M[6] * (float)w + M[7]);
    const float gxb = fmaf(M[8], (float)d0, M[9] * (float)h + M[10] * (float)w + M[11]);

    const float* __restrict__ V = x + (size_t)b * VOL;
    float* __restrict__ owarp = out + WARP_OFF + (size_t)b * VOL +
                                (size_t)d0 * PLANE + (size_t)h * Ww + w;

    float sum = 0.0f;

    #pragma unroll
    for (int kk = 0; kk < DPB / 4; ++kk) {
        f2 q00[4], q01[4], q10[4], q11[4];
        float WLv[4], WHv[4], wy0v[4], wy1v[4], wz0v[4], wz1v[4];

        // ---- phase 1: addresses + weights, issue all 16 loads ----
        #pragma unroll
        for (int j = 0; j < 4; ++j) {
            const int k = kk * 4 + j;
            const float gz = fmaf(dz, (float)k, gzb);
            const float gy = fmaf(dy, (float)k, gyb);
            const float gx = fmaf(dx, (float)k, gxb);

            const float fz = floorf(gz), fy = floorf(gy), fx = floorf(gx);
            const float tz = gz - fz, ty = gy - fy, tx = gx - fx;
            const int iz = (int)fz, iy = (int)fy, ix = (int)fx;

            wz0v[j] = ((unsigned)iz       < (unsigned)Dd) ? (1.0f - tz) : 0.0f;
            wz1v[j] = ((unsigned)(iz + 1) < (unsigned)Dd) ? tz : 0.0f;
            wy0v[j] = ((unsigned)iy       < (unsigned)Hh) ? (1.0f - ty) : 0.0f;
            wy1v[j] = ((unsigned)(iy + 1) < (unsigned)Hh) ? ty : 0.0f;
            const float wx0 = ((unsigned)ix       < (unsigned)Ww) ? (1.0f - tx) : 0.0f;
            const float wx1 = ((unsigned)(ix + 1) < (unsigned)Ww) ? tx : 0.0f;

            const bool right  = (ix >= Ww - 1);
            const bool leftok = (ix >= 0);
            WLv[j] = (right ? 0.0f : wx0) + (leftok ? 0.0f : wx1);
            WHv[j] = (right ? wx0 : 0.0f) + (leftok ? wx1 : 0.0f);

            const int iz0c = min(max(iz, 0), Dd - 1);
            const int iz1c = min(max(iz + 1, 0), Dd - 1);
            const int iy0c = min(max(iy, 0), Hh - 1);
            const int iy1c = min(max(iy + 1, 0), Hh - 1);
            const int ixl  = min(max(ix, 0), Ww - 2);

            const size_t z0 = (size_t)iz0c * PLANE;
            const size_t z1 = (size_t)iz1c * PLANE;
            const int    y0 = iy0c * Ww + ixl;
            const int    y1 = iy1c * Ww + ixl;

            q00[j] = load2(V + z0 + y0);
            q01[j] = load2(V + z0 + y1);
            q10[j] = load2(V + z1 + y0);
            q11[j] = load2(V + z1 + y1);
        }

        // ---- phase 2: combine + store ----
        #pragma unroll
        for (int j = 0; j < 4; ++j) {
            const int k = kk * 4 + j;
            const float v00 = fmaf(WLv[j], q00[j].x, WHv[j] * q00[j].y);
            const float v01 = fmaf(WLv[j], q01[j].x, WHv[j] * q01[j].y);
            const float v10 = fmaf(WLv[j], q10[j].x, WHv[j] * q10[j].y);
            const float v11 = fmaf(WLv[j], q11[j].x, WHv[j] * q11[j].y);

            const float vz0 = fmaf(wy0v[j], v00, wy1v[j] * v01);
            const float vz1 = fmaf(wy0v[j], v10, wy1v[j] * v11);
            const float val = fmaf(wz0v[j], vz0, wz1v[j] * vz1);

            if (NT) {
                __builtin_nontemporal_store(val, &owarp[(size_t)k * PLANE]);
            } else {
                owarp[(size_t)k * PLANE] = val;
            }
            sum += val;
        }
    }

    partial[((size_t)(b * DCH + c) * Hh + h) * Ww + w] = sum;
}

// ---------------- Kernel C: reduce partials -> x_2d, copy y -------------
__global__ __launch_bounds__(256) void reduce_kernel(const float* __restrict__ partial,
                                                     const float* __restrict__ yin,
                                                     float* __restrict__ out) {
    const int idx = blockIdx.x * 256 + threadIdx.x;   // 0..N2D-1
    if (idx >= N2D) return;
    const int b = idx / PLANE;
    const int rem = idx - b * PLANE;
    const float* p = partial + (size_t)b * DCH * PLANE + rem;
    float s = 0.0f;
    #pragma unroll
    for (int c = 0; c < DCH; ++c) s += p[(size_t)c * PLANE];
    out[idx] = s * (1.0f / (float)Dd);
    out[Y_OFF + idx] = yin[idx];
}

// ---------------- Fallback reduce: read x_warp directly -----------------
__global__ __launch_bounds__(256) void reduce_fallback_kernel(const float* __restrict__ yin,
                                                              float* __restrict__ out) {
    const int idx = blockIdx.x * 256 + threadIdx.x;
    if (idx >= N2D) return;
    const int b = idx / PLANE;
    const int rem = idx - b * PLANE;
    const float* p = out + WARP_OFF + (size_t)b * VOL + rem;
    float s = 0.0f;
    #pragma unroll 8
    for (int d = 0; d < Dd; ++d) s += p[(size_t)d * PLANE];
    out[idx] = s * (1.0f / (float)Dd);
    out[Y_OFF + idx] = yin[idx];
}

extern "C" void kernel_launch(void* const* d_in, const int* in_sizes, int n_in,
                              void* d_out, int out_size, void* d_ws, size_t ws_size,
                              hipStream_t stream) {
    const float* x    = (const float*)d_in[0];
    const float* yin  = (const float*)d_in[1];
    const float* rot0 = (const float*)d_in[2];
    const float* rot1 = (const float*)d_in[3];
    const float* rot2 = (const float*)d_in[4];
    const float* tr1  = (const float*)d_in[5];
    const float* tr2  = (const float*)d_in[6];
    const float* cp   = (const float*)d_in[7];

    float* mats = (float*)d_ws;
    float* partial = (float*)d_ws + 64;
    const size_t need = (64 + (size_t)Bn * DCH * PLANE) * sizeof(float);

    mats_kernel<<<1, 64, 0, stream>>>(rot0, rot1, rot2, tr1, tr2, cp, mats);

    const int nblocks = Bn * DCH * Hh;   // 6144
    if (ws_size >= need) {
        warp_kernel<true><<<nblocks, Ww, 0, stream>>>(x, mats, (float*)d_out, partial);
        reduce_kernel<<<(N2D + 255) / 256, 256, 0, stream>>>(partial, yin, (float*)d_out);
    } else {
        warp_kernel<false><<<nblocks, Ww, 0, stream>>>(x, mats, (float*)d_out, mats /*unused*/);
        reduce_fallback_kernel<<<(N2D + 255) / 256, 256, 0, stream>>>(yin, (float*)d_out);
    }
}

// Round 5
// 75.507 us; speedup vs baseline: 1.8673x; 1.0816x over previous
//
#include <hip/hip_runtime.h>

#define Bn 4
#define Dd 128
#define Hh 192
#define Ww 192

#define PLANE (Hh * Ww)           // 36864
#define VOL   (Dd * PLANE)
#define N2D   (Bn * PLANE)
#define WARP_OFF ((size_t)N2D)
#define Y_OFF (WARP_OFF + (size_t)Bn * VOL)

// tile geometry
#define DT 8
#define HT 8
#define WT 16
#define NDB (Dd / DT)    // 16 d-blocks
#define NHB (Hh / HT)    // 24
#define NWB (Ww / WT)    // 12
#define NBLK (Bn * NDB * NHB * NWB)   // 18432

// LDS box (fixed)
#define SZ 16
#define SY 16
#define SXP 28           // x stride in floats (7 dwordx4)
#define SXQ 7            // q-words per row
#define STAGE_IT ((SZ * SY * SXQ) / 256)   // 7

typedef float f2 __attribute__((ext_vector_type(2)));
typedef f2 __attribute__((aligned(4))) f2u;
__device__ __forceinline__ f2 load2(const float* p) { return *(const f2u*)p; }

// ---------------- Kernel A: per-batch affine matrices ----------------
__global__ void mats_kernel(const float* __restrict__ rot0,
                            const float* __restrict__ rot1,
                            const float* __restrict__ rot2,
                            const float* __restrict__ tr1,
                            const float* __restrict__ tr2,
                            const float* __restrict__ cp,
                            float* __restrict__ mats) {
    int b = threadIdx.x;
    if (b >= Bn) return;
    float z = rot0[b], y = rot1[b], x = rot2[b];
    float cz = cosf(z), sz = sinf(z);
    float cy = cosf(y), sy = sinf(y);
    float cx = cosf(x), sx = sinf(x);
    float R00 = cz * cy;
    float R01 = -sz * cx + cz * sy * sx;
    float R02 = sz * sx + cz * sy * cx;
    float R10 = sz * cy;
    float R11 = cz * cx + sz * sy * sx;
    float R12 = -cz * sx + sz * sy * cx;
    float R20 = -sy;
    float R21 = cy * sx;
    float R22 = cy * cx;
    float c0 = cp[b * 3 + 0], c1 = cp[b * 3 + 1], c2 = cp[b * 3 + 2];
    float ty = tr1[b] * (float)Hh;
    float tx = tr2[b] * (float)Ww;
    float m03 = -(R00 * c0 + R01 * c1 + R02 * c2) + c0;
    float m13 = -(R10 * c0 + R11 * c1 + R12 * c2) + ty + c1;
    float m23 = -(R20 * c0 + R21 * c1 + R22 * c2) + tx + c2;
    float* M = mats + b * 12;
    M[0] = R00; M[1]  = R01; M[2]  = R02; M[3]  = m03;
    M[4] = R10; M[5]  = R11; M[6]  = R12; M[7]  = m13;
    M[8] = R20; M[9]  = R21; M[10] = R22; M[11] = m23;
}

// ---------------- Kernel B: LDS-tiled warp ----------------
template <bool NT, bool WP>
__global__ __launch_bounds__(256) void warp_tiled(const float* __restrict__ x,
                                                  const float* __restrict__ mats,
                                                  float* __restrict__ out,
                                                  float* __restrict__ partial) {
    __shared__ __align__(16) float box[SZ * SY * SXP];   // 28672 B
    __shared__ float sums[256];

    // ---- XCD-aware block decode ----
    const int g   = blockIdx.x;
    const int xcd = g & 7;
    const int wl  = xcd * (NBLK / 8) + (g >> 3);
    const int wblk = wl % NWB;
    const int t1   = wl / NWB;
    const int hblk = t1 % NHB;
    const int t2   = t1 / NHB;
    const int dblk = t2 & (NDB - 1);
    const int b    = t2 >> 4;

    const int d0 = dblk * DT, h0 = hblk * HT, w0 = wblk * WT;

    const int t   = threadIdx.x;
    const int w_in = t & 15;
    const int h_in = (t >> 4) & 7;
    const int dq   = t >> 7;          // 0/1

    const float* M = mats + b * 12;
    const float A0 = M[0], B0 = M[1], C0 = M[2], E0 = M[3];
    const float A1 = M[4], B1 = M[5], C1 = M[6], E1 = M[7];
    const float A2 = M[8], B2 = M[9], C2 = M[10], E2 = M[11];

    // ---- runtime source bounding box over the 8 tile corners ----
    const float dlo = (float)d0, dhi = (float)(d0 + DT - 1);
    const float hlo = (float)h0, hhi = (float)(h0 + HT - 1);
    const float wlo = (float)w0, whi = (float)(w0 + WT - 1);

    const float loZ = E0 + fminf(A0 * dlo, A0 * dhi) + fminf(B0 * hlo, B0 * hhi) + fminf(C0 * wlo, C0 * whi);
    const float hiZ = E0 + fmaxf(A0 * dlo, A0 * dhi) + fmaxf(B0 * hlo, B0 * hhi) + fmaxf(C0 * wlo, C0 * whi);
    const float loY = E1 + fminf(A1 * dlo, A1 * dhi) + fminf(B1 * hlo, B1 * hhi) + fminf(C1 * wlo, C1 * whi);
    const float hiY = E1 + fmaxf(A1 * dlo, A1 * dhi) + fmaxf(B1 * hlo, B1 * hhi) + fmaxf(C1 * wlo, C1 * whi);
    const float loX = E2 + fminf(A2 * dlo, A2 * dhi) + fminf(B2 * hlo, B2 * hhi) + fminf(C2 * wlo, C2 * whi);
    const float hiX = E2 + fmaxf(A2 * dlo, A2 * dhi) + fmaxf(B2 * hlo, B2 * hhi) + fmaxf(C2 * wlo, C2 * whi);

    const int lz = max(0, (int)floorf(loZ));
    const int hz = min(Dd - 1, (int)floorf(hiZ) + 1);
    const int ly = max(0, (int)floorf(loY));
    const int hy = min(Hh - 1, (int)floorf(hiY) + 1);
    const int lx = max(0, (int)floorf(loX));
    const int lx4 = lx & ~3;
    const int hx = min(Ww - 1, (int)floorf(hiX) + 1);

    const bool fits = (hz - lz <= SZ - 1) && (hy - ly <= SY - 1) && (hx - lx4 <= SXP - 1);

    const float* __restrict__ V = x + (size_t)b * VOL;
    float* __restrict__ obase = out + WARP_OFF + (size_t)b * VOL +
                                (size_t)h0 * Ww + (size_t)w0 + (size_t)h_in * Ww + w_in;

    const float hb0 = B0 * (float)(h0 + h_in) + C0 * (float)(w0 + w_in) + E0;
    const float hb1 = B1 * (float)(h0 + h_in) + C1 * (float)(w0 + w_in) + E1;
    const float hb2 = B2 * (float)(h0 + h_in) + C2 * (float)(w0 + w_in) + E2;

    float sum = 0.0f;

    if (fits) {
        // ---- stage the box: dense, q-aligned dwordx4 loads ----
        const int qbase = lx4 >> 2;
        #pragma unroll
        for (int i = 0; i < STAGE_IT; ++i) {
            const int e  = i * 256 + t;
            const int z  = e / (SY * SXQ);            // /112
            const int r  = e - z * (SY * SXQ);
            const int yy = r / SXQ;                   // /7
            const int qc = r - yy * SXQ;
            const int zz = min(max(lz + z, 0), Dd - 1);
            const int yv = min(max(ly + yy, 0), Hh - 1);
            const int qcol = min(qbase + qc, Ww / 4 - 1);
            const float4 v = *(const float4*)(V + (size_t)zz * PLANE + yv * Ww + 4 * qcol);
            *(float4*)&box[(z * SY + yy) * SXP + 4 * qc] = v;
        }
        __syncthreads();

        // ---- sample 4 voxels from LDS ----
        #pragma unroll
        for (int j = 0; j < 4; ++j) {
            const int d_in = dq + 2 * j;
            const float fd = (float)(d0 + d_in);
            const float gz = fmaf(A0, fd, hb0);
            const float gy = fmaf(A1, fd, hb1);
            const float gx = fmaf(A2, fd, hb2);

            const float fz = floorf(gz), fy = floorf(gy), fx = floorf(gx);
            const float tz = gz - fz, ty = gy - fy, tx = gx - fx;
            const int iz = (int)fz, iy = (int)fy, ix = (int)fx;

            const float wz0 = ((unsigned)iz       < (unsigned)Dd) ? (1.0f - tz) : 0.0f;
            const float wz1 = ((unsigned)(iz + 1) < (unsigned)Dd) ? tz : 0.0f;
            const float wy0 = ((unsigned)iy       < (unsigned)Hh) ? (1.0f - ty) : 0.0f;
            const float wy1 = ((unsigned)(iy + 1) < (unsigned)Hh) ? ty : 0.0f;
            const float wx0 = ((unsigned)ix       < (unsigned)Ww) ? (1.0f - tx) : 0.0f;
            const float wx1 = ((unsigned)(ix + 1) < (unsigned)Ww) ? tx : 0.0f;

            const bool right  = (ix >= Ww - 1);
            const bool leftok = (ix >= 0);
            const float WL = (right ? 0.0f : wx0) + (leftok ? 0.0f : wx1);
            const float WH = (right ? wx0 : 0.0f) + (leftok ? wx1 : 0.0f);

            const int zc0 = min(max(iz, 0), Dd - 1) - lz;
            const int zc1 = min(max(iz + 1, 0), Dd - 1) - lz;
            const int yc0 = min(max(iy, 0), Hh - 1) - ly;
            const int yc1 = min(max(iy + 1, 0), Hh - 1) - ly;
            const int ixl = min(max(ix, 0), Ww - 2);
            const int col = max(ixl - lx4, 0);

            const int b00 = (zc0 * SY + yc0) * SXP + col;
            const int b01 = (zc0 * SY + yc1) * SXP + col;
            const int b10 = (zc1 * SY + yc0) * SXP + col;
            const int b11 = (zc1 * SY + yc1) * SXP + col;

            const float v00 = fmaf(WL, box[b00], WH * box[b00 + 1]);
            const float v01 = fmaf(WL, box[b01], WH * box[b01 + 1]);
            const float v10 = fmaf(WL, box[b10], WH * box[b10 + 1]);
            const float v11 = fmaf(WL, box[b11], WH * box[b11 + 1]);

            const float vz0 = fmaf(wy0, v00, wy1 * v01);
            const float vz1 = fmaf(wy0, v10, wy1 * v11);
            const float val = fmaf(wz0, vz0, wz1 * vz1);

            float* op = obase + (size_t)(d0 + d_in) * PLANE;
            if (NT) __builtin_nontemporal_store(val, op);
            else    *op = val;
            sum += val;
        }
    } else {
        // ---- fallback: direct global gather (proven path) ----
        #pragma unroll
        for (int j = 0; j < 4; ++j) {
            const int d_in = dq + 2 * j;
            const float fd = (float)(d0 + d_in);
            const float gz = fmaf(A0, fd, hb0);
            const float gy = fmaf(A1, fd, hb1);
            const float gx = fmaf(A2, fd, hb2);

            const float fz = floorf(gz), fy = floorf(gy), fx = floorf(gx);
            const float tz = gz - fz, ty = gy - fy, tx = gx - fx;
            const int iz = (int)fz, iy = (int)fy, ix = (int)fx;

            const float wz0 = ((unsigned)iz       < (unsigned)Dd) ? (1.0f - tz) : 0.0f;
            const float wz1 = ((unsigned)(iz + 1) < (unsigned)Dd) ? tz : 0.0f;
            const float wy0 = ((unsigned)iy       < (unsigned)Hh) ? (1.0f - ty) : 0.0f;
            const float wy1 = ((unsigned)(iy + 1) < (unsigned)Hh) ? ty : 0.0f;
            const float wx0 = ((unsigned)ix       < (unsigned)Ww) ? (1.0f - tx) : 0.0f;
            const float wx1 = ((unsigned)(ix + 1) < (unsigned)Ww) ? tx : 0.0f;

            const bool right  = (ix >= Ww - 1);
            const bool leftok = (ix >= 0);
            const float WL = (right ? 0.0f : wx0) + (leftok ? 0.0f : wx1);
            const float WH = (right ? wx0 : 0.0f) + (leftok ? wx1 : 0.0f);

            const int iz0c = min(max(iz, 0), Dd - 1);
            const int iz1c = min(max(iz + 1, 0), Dd - 1);
            const int iy0c = min(max(iy, 0), Hh - 1);
            const int iy1c = min(max(iy + 1, 0), Hh - 1);
            const int ixl  = min(max(ix, 0), Ww - 2);

            const size_t z0 = (size_t)iz0c * PLANE;
            const size_t z1 = (size_t)iz1c * PLANE;
            const int    y0 = iy0c * Ww + ixl;
            const int    y1 = iy1c * Ww + ixl;

            const f2 q00 = load2(V + z0 + y0);
            const f2 q01 = load2(V + z0 + y1);
            const f2 q10 = load2(V + z1 + y0);
            const f2 q11 = load2(V + z1 + y1);

            const float v00 = fmaf(WL, q00.x, WH * q00.y);
            const float v01 = fmaf(WL, q01.x, WH * q01.y);
            const float v10 = fmaf(WL, q10.x, WH * q10.y);
            const float v11 = fmaf(WL, q11.x, WH * q11.y);

            const float vz0 = fmaf(wy0, v00, wy1 * v01);
            const float vz1 = fmaf(wy0, v10, wy1 * v11);
            const float val = fmaf(wz0, vz0, wz1 * vz1);

            float* op = obase + (size_t)(d0 + d_in) * PLANE;
            if (NT) __builtin_nontemporal_store(val, op);
            else    *op = val;
            sum += val;
        }
    }

    // ---- combine the two d-interleaved halves -> per-block partial ----
    if (WP) {
        __syncthreads();
        sums[t] = sum;
        __syncthreads();
        if (t < 128) {
            const float s = sums[t] + sums[t + 128];
            partial[((size_t)(b * NDB + dblk) * Hh + (h0 + h_in)) * Ww + (w0 + w_in)] = s;
        }
    }
}

// ---------------- Kernel C: reduce partials -> x_2d, copy y -------------
__global__ __launch_bounds__(256) void reduce_kernel(const float* __restrict__ partial,
                                                     const float* __restrict__ yin,
                                                     float* __restrict__ out) {
    const int idx = blockIdx.x * 256 + threadIdx.x;
    if (idx >= N2D) return;
    const int b = idx / PLANE;
    const int rem = idx - b * PLANE;
    const float* p = partial + (size_t)b * NDB * PLANE + rem;
    float s = 0.0f;
    #pragma unroll
    for (int c = 0; c < NDB; ++c) s += p[(size_t)c * PLANE];
    out[idx] = s * (1.0f / (float)Dd);
    out[Y_OFF + idx] = yin[idx];
}

// ---------------- Fallback reduce: read x_warp directly -----------------
__global__ __launch_bounds__(256) void reduce_fallback_kernel(const float* __restrict__ yin,
                                                              float* __restrict__ out) {
    const int idx = blockIdx.x * 256 + threadIdx.x;
    if (idx >= N2D) return;
    const int b = idx / PLANE;
    const int rem = idx - b * PLANE;
    const float* p = out + WARP_OFF + (size_t)b * VOL + rem;
    float s = 0.0f;
    #pragma unroll 8
    for (int d = 0; d < Dd; ++d) s += p[(size_t)d * PLANE];
    out[idx] = s * (1.0f / (float)Dd);
    out[Y_OFF + idx] = yin[idx];
}

extern "C" void kernel_launch(void* const* d_in, const int* in_sizes, int n_in,
                              void* d_out, int out_size, void* d_ws, size_t ws_size,
                              hipStream_t stream) {
    const float* x    = (const float*)d_in[0];
    const float* yin  = (const float*)d_in[1];
    const float* rot0 = (const float*)d_in[2];
    const float* rot1 = (const float*)d_in[3];
    const float* rot2 = (const float*)d_in[4];
    const float* tr1  = (const float*)d_in[5];
    const float* tr2  = (const float*)d_in[6];
    const float* cp   = (const float*)d_in[7];

    float* mats = (float*)d_ws;
    float* partial = (float*)d_ws + 64;
    const size_t need = (64 + (size_t)Bn * NDB * PLANE) * sizeof(float);

    mats_kernel<<<1, 64, 0, stream>>>(rot0, rot1, rot2, tr1, tr2, cp, mats);

    if (ws_size >= need) {
        warp_tiled<true, true><<<NBLK, 256, 0, stream>>>(x, mats, (float*)d_out, partial);
        reduce_kernel<<<(N2D + 255) / 256, 256, 0, stream>>>(partial, yin, (float*)d_out);
    } else {
        warp_tiled<true, false><<<NBLK, 256, 0, stream>>>(x, mats, (float*)d_out, partial);
        reduce_fallback_kernel<<<(N2D + 255) / 256, 256, 0, stream>>>(yin, (float*)d_out);
    }
}